// Round 2
// baseline (2888.700 us; speedup 1.0000x reference)
//
#include <hip/hip_runtime.h>
#include <cstdint>

#define HID 250
#define NIN 128
#define BATCH 512
#define N1 (BATCH * HID)          // 128000 layer-1/2 neuron-chains
#define T_TOTAL 1000
#define OUT_HALF 1024000          // 1000*512*2 floats per output tensor

// ---------------------------------------------------------------------------
// GEMM1: cur[r][c] = (sum_k x[r][k]*W1[k][c]) + b1[c]  -- pure f32.
// Exactly replicates BLAS sgemm: k ascending, fused fma into a single
// accumulator per element, bias added AFTER with a separate f32 rounding.
// Block = 128 threads; 32 rows x 250 cols per block.
// ---------------------------------------------------------------------------
__global__ __launch_bounds__(128) void gemm1_f32(
    const float* __restrict__ x,   // [M][128]
    const float* __restrict__ W1,  // [128][250]
    const float* __restrict__ b1,  // [250]
    float* __restrict__ cur,       // [M][250]
    int M)
{
#pragma clang fp contract(off)
    __shared__ float xs[32 * NIN];   // 16 KB
    const int tid = threadIdx.x;
    const long rowBase = (long)blockIdx.x * 32;

    const float* xsrc = x + rowBase * NIN;
    #pragma unroll
    for (int i = 0; i < 32; ++i) xs[tid + i * 128] = xsrc[tid + i * 128];
    __syncthreads();

    const int c0 = tid;
    const int c1 = tid + 128;
    const bool has1 = (c1 < HID);

    float acc0[32], acc1[32];
    #pragma unroll
    for (int r = 0; r < 32; ++r) { acc0[r] = 0.0f; acc1[r] = 0.0f; }

    for (int k = 0; k < NIN; ++k) {
        const float w0 = W1[k * HID + c0];
        const float w1 = has1 ? W1[k * HID + c1] : 0.0f;
        #pragma unroll
        for (int r = 0; r < 32; ++r) {
            const float xv = xs[r * NIN + k];       // wave-broadcast
            acc0[r] = __builtin_fmaf(xv, w0, acc0[r]);   // fused, like sgemm
            acc1[r] = __builtin_fmaf(xv, w1, acc1[r]);
        }
    }

    const float bb0 = b1[c0];
    const float bb1 = has1 ? b1[c1] : 0.0f;
    for (int r = 0; r < 32; ++r) {
        long row = rowBase + r;
        cur[row * HID + c0] = acc0[r] + bb0;        // contract(off): plain add
        if (has1) cur[row * HID + c1] = acc1[r] + bb1;
    }
}

// ---------------------------------------------------------------------------
// LIF scan layers 1/2: m = ((0.9f*m) + cur) - reset, each op rounded f32,
// matching numpy's elementwise evaluation. Spike as byte.
// ---------------------------------------------------------------------------
__global__ __launch_bounds__(256) void scan_f32(
    const float* __restrict__ cur,   // [Tc][N1]
    uint8_t* __restrict__ spk,       // [Tc][N1]
    float* __restrict__ state,       // [N1]
    int Tc)
{
#pragma clang fp contract(off)
    const int n = blockIdx.x * 256 + threadIdx.x;   // grid = 500*256 == N1
    float m = state[n];
    for (int t = 0; t < Tc; ++t) {
        float c = cur[(long)t * N1 + n];
        float reset = (m > 1.0f) ? 1.0f : 0.0f;
        float tmp = 0.9f * m;    // round
        tmp = tmp + c;           // round
        m = tmp - reset;         // round
        spk[(long)t * N1 + n] = (m > 1.0f) ? (uint8_t)1 : (uint8_t)0;
    }
    state[n] = m;
}

// ---------------------------------------------------------------------------
// GEMM2: cur[r][c] = (ordered sum_{k asc: s[r][k]} W2[k][c]) + b2[c].
// Ascending-k conditional add chain == sgemm bit-exactly (operands are 0/1).
// Ordered ballot compaction builds the active list; 8 rows per 256-thr block.
// ---------------------------------------------------------------------------
__global__ __launch_bounds__(256) void gemm2_f32(
    const uint8_t* __restrict__ s,   // [M][250]
    const float* __restrict__ W2,    // [250][250]
    const float* __restrict__ b2,    // [250]
    float* __restrict__ cur,         // [M][250]
    int M)
{
#pragma clang fp contract(off)
    __shared__ int list[256];
    __shared__ int cnts[4];
    const int tid = threadIdx.x;
    const int wave = tid >> 6, lane = tid & 63;
    const long row0 = (long)blockIdx.x * 8;

    for (int rr = 0; rr < 8; ++rr) {
        const long row = row0 + rr;
        const int k = wave * 64 + lane;              // 0..255
        const bool sp = (k < HID) && s[row * HID + k];
        unsigned long long mask = __ballot(sp);
        if (lane == 0) cnts[wave] = __popcll(mask);
        __syncthreads();
        int off = 0;
        #pragma unroll
        for (int w = 0; w < 4; ++w) if (w < wave) off += cnts[w];
        const int nact = cnts[0] + cnts[1] + cnts[2] + cnts[3];
        if (sp) list[off + __popcll(mask & ((1ull << lane) - 1ull))] = k;
        __syncthreads();

        if (tid < HID) {
            float acc = 0.0f;
            for (int j = 0; j < nact; ++j)
                acc = acc + W2[list[j] * HID + tid];   // L2-resident row, asc k
            cur[row * HID + tid] = acc + b2[tid];
        }
        __syncthreads();   // protect list/cnts before next row
    }
}

// ---------------------------------------------------------------------------
// GEMM3: cur3[r][c] = (ordered sum_{k asc: s[r][k]} W3[k][c]) + b3[c].
// One wave per row; 4 sequential 64-wide ballot chunks keep ascending order;
// lanes 0/1 then do the serial ordered add chain (nact ~ 10-30).
// ---------------------------------------------------------------------------
__global__ __launch_bounds__(256) void gemm3_f32(
    const uint8_t* __restrict__ s,   // [M][250]
    const float* __restrict__ W3,    // [250][2]
    const float* __restrict__ b3,    // [2]
    float* __restrict__ cur3,        // [M][2]
    int M)
{
#pragma clang fp contract(off)
    __shared__ int wl[4][256];
    const int tid = threadIdx.x;
    const int wave = tid >> 6, lane = tid & 63;
    const long row = (long)blockIdx.x * 4 + wave;

    int base = 0;
    #pragma unroll
    for (int c = 0; c < 4; ++c) {
        const int k = c * 64 + lane;
        const bool sp = (k < HID) && s[row * HID + k];
        unsigned long long mask = __ballot(sp);
        if (sp) wl[wave][base + __popcll(mask & ((1ull << lane) - 1ull))] = k;
        base += __popcll(mask);      // wave-uniform
    }
    __syncthreads();

    if (lane < 2) {
        const int nact = base;
        float acc = 0.0f;
        for (int j = 0; j < nact; ++j)
            acc = acc + W3[wl[wave][j] * 2 + lane];
        cur3[row * 2 + lane] = acc + b3[lane];
    }
}

// ---------------------------------------------------------------------------
// Output scan: writes spikes (f32 0/1) and mem_rec (f32) into d_out.
// ---------------------------------------------------------------------------
__global__ __launch_bounds__(256) void scan3_f32(
    const float* __restrict__ cur3,  // [Tc][1024]
    float* __restrict__ state,       // [1024]
    float* __restrict__ out,         // spikes @0, mem @OUT_HALF
    int t0, int Tc)
{
#pragma clang fp contract(off)
    const int n = blockIdx.x * 256 + threadIdx.x;   // grid = 4*256 == 1024
    float m = state[n];
    for (int t = 0; t < Tc; ++t) {
        float c = cur3[(long)t * 1024 + n];
        float reset = (m > 1.0f) ? 1.0f : 0.0f;
        float tmp = 0.9f * m;
        tmp = tmp + c;
        m = tmp - reset;
        long o = (long)(t0 + t) * 1024 + n;
        out[o] = (m > 1.0f) ? 1.0f : 0.0f;
        out[OUT_HALF + o] = m;
    }
    state[n] = m;
}

// ---------------------------------------------------------------------------
extern "C" void kernel_launch(void* const* d_in, const int* in_sizes, int n_in,
                              void* d_out, int out_size, void* d_ws, size_t ws_size,
                              hipStream_t stream) {
    const float* x  = (const float*)d_in[0];
    const float* W1 = (const float*)d_in[1];
    const float* b1 = (const float*)d_in[2];
    const float* W2 = (const float*)d_in[3];
    const float* b2 = (const float*)d_in[4];
    const float* W3 = (const float*)d_in[5];
    const float* b3 = (const float*)d_in[6];
    float* out = (float*)d_out;

    char* w = (char*)d_ws;
    size_t off = 0;
    auto alloc = [&](size_t bytes) -> void* {
        void* p = (void*)(w + off);
        off = (off + bytes + 255) & ~(size_t)255;
        return p;
    };

    float* m1 = (float*)alloc((size_t)N1 * 4);      // 512,000 B
    float* m2 = (float*)alloc((size_t)N1 * 4);      // 512,000 B
    float* m3 = (float*)alloc(1024 * 4);            // 4,096 B
    const size_t fixed = off;                        // states, zeroed each call

    // chunk size from workspace: per-step = cur3(4K) + sbuf(125K) + cur(500K)
    const size_t perT = 4096 + 128000 + 512000;
    long tc_budget = ((long)ws_size - (long)fixed - 4096) / (long)perT;
    int Tc = (int)(tc_budget < 1 ? 1 : (tc_budget > T_TOTAL ? T_TOTAL : tc_budget));

    float*   cur3 = (float*)alloc((size_t)Tc * 4096);
    uint8_t* sbuf = (uint8_t*)alloc((size_t)Tc * 128000);
    float*   cur  = (float*)alloc((size_t)Tc * 512000);

    hipMemsetAsync(d_ws, 0, fixed, stream);   // zero membrane states

    for (int t0 = 0; t0 < T_TOTAL; t0 += Tc) {
        const int tc = (T_TOTAL - t0 < Tc) ? (T_TOTAL - t0) : Tc;
        const int M = tc * BATCH;   // divisible by 512 -> by 32/8/4

        gemm1_f32<<<M / 32, 128, 0, stream>>>(x + (size_t)t0 * BATCH * NIN,
                                              W1, b1, cur, M);
        scan_f32<<<N1 / 256, 256, 0, stream>>>(cur, sbuf, m1, tc);
        gemm2_f32<<<M / 8, 256, 0, stream>>>(sbuf, W2, b2, cur, M);
        scan_f32<<<N1 / 256, 256, 0, stream>>>(cur, sbuf, m2, tc);
        gemm3_f32<<<M / 4, 256, 0, stream>>>(sbuf, W3, b3, cur3, M);
        scan3_f32<<<4, 256, 0, stream>>>(cur3, m3, out, t0, tc);
    }
}

// Round 3
// 2592.857 us; speedup vs baseline: 1.1141x; 1.1141x over previous
//
#include <hip/hip_runtime.h>
#include <cstdint>

#define HID 250
#define NIN 128
#define BATCH 512
#define N1 (BATCH * HID)          // 128000 layer-1/2 neuron-chains
#define T_TOTAL 1000
#define OUT_HALF 1024000          // 1000*512*2 floats per output tensor

// ---------------------------------------------------------------------------
// GEMM1 v2: register-tiled. Block = 256 thr, tile 64 rows x 256 cols (250 used).
// Thread (ri=tid>>4, ci=tid&15): rows 4ri..4ri+3, cols {64j + 4ci + u}.
// x staged TRANSPOSED in LDS (xT[k][row], stride 68) -> per-k A read is one
// broadcast ds_read_b128 (4 distinct addrs/wave = free). W read as coalesced
// float4 from global (L2-resident, 128 KB).
// Numerics: per output element, single accumulator, fused fmaf, k=0..127
// ascending — bit-identical to R2's gemm1.
// ---------------------------------------------------------------------------
__global__ __launch_bounds__(256, 4) void gemm1_v2(
    const float* __restrict__ x,   // [M][128]
    const float* __restrict__ W1,  // [128][250]
    const float* __restrict__ b1,  // [250]
    float* __restrict__ cur,       // [M][250]
    int M)
{
#pragma clang fp contract(off)
    __shared__ __align__(16) float xT[128 * 68];   // 34816 B
    const int tid  = threadIdx.x;
    const int lane = tid & 63, wave = tid >> 6;
    const long rowBase = (long)blockIdx.x * 64;

    // stage x[rowBase..+64][0..128) transposed: thread loads float4 of row
    // `lane` at k-quad kq = 4i+wave; LDS writes are conflict-free (addr=c+lane).
    const float* xb = x + rowBase * NIN;
    #pragma unroll
    for (int i = 0; i < 8; ++i) {
        const int kq = i * 4 + wave;
        const float4 v = *(const float4*)(xb + (long)lane * NIN + kq * 4);
        xT[(4 * kq + 0) * 68 + lane] = v.x;
        xT[(4 * kq + 1) * 68 + lane] = v.y;
        xT[(4 * kq + 2) * 68 + lane] = v.z;
        xT[(4 * kq + 3) * 68 + lane] = v.w;
    }
    __syncthreads();

    const int ri = tid >> 4;   // 0..15 -> rows 4ri..4ri+3
    const int ci = tid & 15;   // 0..15 -> col quads 64j + 4ci

    float acc[4][16];
    #pragma unroll
    for (int r = 0; r < 4; ++r)
        #pragma unroll
        for (int c = 0; c < 16; ++c) acc[r][c] = 0.0f;

    for (int k = 0; k < NIN; ++k) {
        const float4 a = *(const float4*)&xT[k * 68 + 4 * ri];  // broadcast
        const float* wr = W1 + k * HID;
        float w[16];
        #pragma unroll
        for (int j = 0; j < 3; ++j) {
            const float4 wv = *(const float4*)(wr + 64 * j + 4 * ci);
            w[4*j+0] = wv.x; w[4*j+1] = wv.y; w[4*j+2] = wv.z; w[4*j+3] = wv.w;
        }
        {   // j=3: cols 192+4ci .. +3, guard the 250 edge (no OOB float4)
            const int c0 = 192 + 4 * ci;
            if (ci < 14) {
                const float4 wv = *(const float4*)(wr + c0);
                w[12] = wv.x; w[13] = wv.y; w[14] = wv.z; w[15] = wv.w;
            } else {
                #pragma unroll
                for (int u = 0; u < 4; ++u)
                    w[12+u] = (c0 + u < HID) ? wr[c0 + u] : 0.0f;
            }
        }
        const float av[4] = {a.x, a.y, a.z, a.w};
        #pragma unroll
        for (int r = 0; r < 4; ++r)
            #pragma unroll
            for (int c = 0; c < 16; ++c)
                acc[r][c] = __builtin_fmaf(av[r], w[c], acc[r][c]);
    }

    // epilogue: +bias (separately rounded), float2 stores (8B-aligned: 250 even)
    #pragma unroll
    for (int j = 0; j < 4; ++j) {
        #pragma unroll
        for (int p = 0; p < 2; ++p) {
            const int cp = 64 * j + 4 * ci + 2 * p;
            if (cp < HID) {
                const float b0 = b1[cp], b1v = b1[cp + 1];
                #pragma unroll
                for (int r = 0; r < 4; ++r) {
                    const long row = rowBase + 4 * ri + r;
                    float2 o;
                    o.x = acc[r][4*j + 2*p]     + b0;
                    o.y = acc[r][4*j + 2*p + 1] + b1v;
                    *(float2*)(cur + row * HID + cp) = o;
                }
            }
        }
    }
}

// ---------------------------------------------------------------------------
// LIF scan layers 1/2: unroll x4, loads hoisted (independent) ahead of the
// dependent recurrence. Arithmetic per element identical to R2.
// ---------------------------------------------------------------------------
__global__ __launch_bounds__(256) void scan_f32(
    const float* __restrict__ cur,   // [Tc][N1]
    uint8_t* __restrict__ spk,       // [Tc][N1]
    float* __restrict__ state,       // [N1]
    int Tc)
{
#pragma clang fp contract(off)
    const int n = blockIdx.x * 256 + threadIdx.x;   // grid = 500*256 == N1
    float m = state[n];
    int t = 0;
    for (; t + 4 <= Tc; t += 4) {
        const long base = (long)t * N1 + n;
        const float c0 = cur[base];
        const float c1 = cur[base + N1];
        const float c2 = cur[base + 2L * N1];
        const float c3 = cur[base + 3L * N1];
        float r, tmp;
        r = (m > 1.0f) ? 1.0f : 0.0f; tmp = 0.9f * m; tmp = tmp + c0; m = tmp - r;
        spk[base]           = (m > 1.0f) ? (uint8_t)1 : (uint8_t)0;
        r = (m > 1.0f) ? 1.0f : 0.0f; tmp = 0.9f * m; tmp = tmp + c1; m = tmp - r;
        spk[base + N1]      = (m > 1.0f) ? (uint8_t)1 : (uint8_t)0;
        r = (m > 1.0f) ? 1.0f : 0.0f; tmp = 0.9f * m; tmp = tmp + c2; m = tmp - r;
        spk[base + 2L * N1] = (m > 1.0f) ? (uint8_t)1 : (uint8_t)0;
        r = (m > 1.0f) ? 1.0f : 0.0f; tmp = 0.9f * m; tmp = tmp + c3; m = tmp - r;
        spk[base + 3L * N1] = (m > 1.0f) ? (uint8_t)1 : (uint8_t)0;
    }
    for (; t < Tc; ++t) {
        const long base = (long)t * N1 + n;
        const float c = cur[base];
        const float r = (m > 1.0f) ? 1.0f : 0.0f;
        float tmp = 0.9f * m; tmp = tmp + c; m = tmp - r;
        spk[base] = (m > 1.0f) ? (uint8_t)1 : (uint8_t)0;
    }
    state[n] = m;
}

// ---------------------------------------------------------------------------
// GEMM2 v2: 2 rows interleaved per thread -> 2 independent load/add chains.
// Per-row ascending-k ordered add chain unchanged (bit-exact).
// ---------------------------------------------------------------------------
__global__ __launch_bounds__(256) void gemm2_f32(
    const uint8_t* __restrict__ s,   // [M][250]
    const float* __restrict__ W2,    // [250][250]
    const float* __restrict__ b2,    // [250]
    float* __restrict__ cur,         // [M][250]
    int M)
{
#pragma clang fp contract(off)
    __shared__ int lista[256], listb[256];
    __shared__ int cntsa[4], cntsb[4];
    const int tid = threadIdx.x;
    const int wave = tid >> 6, lane = tid & 63;
    const long row0 = (long)blockIdx.x * 16;
    const unsigned long long lmask = (1ull << lane) - 1ull;

    for (int rr = 0; rr < 8; ++rr) {
        const long ra = row0 + 2 * rr, rb = ra + 1;
        const int k = wave * 64 + lane;              // 0..255
        const bool ina = (k < HID) && s[ra * HID + k];
        const bool inb = (k < HID) && s[rb * HID + k];
        const unsigned long long ma = __ballot(ina);
        const unsigned long long mb = __ballot(inb);
        if (lane == 0) { cntsa[wave] = __popcll(ma); cntsb[wave] = __popcll(mb); }
        __syncthreads();
        int offa = 0, offb = 0, na = 0, nb = 0;
        #pragma unroll
        for (int w = 0; w < 4; ++w) {
            if (w < wave) { offa += cntsa[w]; offb += cntsb[w]; }
            na += cntsa[w]; nb += cntsb[w];
        }
        if (ina) lista[offa + __popcll(ma & lmask)] = k;
        if (inb) listb[offb + __popcll(mb & lmask)] = k;
        __syncthreads();

        if (tid < HID) {
            float acca = 0.0f, accb = 0.0f;
            const int nmin = (na < nb) ? na : nb;
            int j = 0;
            for (; j < nmin; ++j) {
                acca = acca + W2[lista[j] * HID + tid];
                accb = accb + W2[listb[j] * HID + tid];
            }
            for (; j < na; ++j) acca = acca + W2[lista[j] * HID + tid];
            for (; j < nb; ++j) accb = accb + W2[listb[j] * HID + tid];
            const float bb = b2[tid];
            cur[ra * HID + tid] = acca + bb;
            cur[rb * HID + tid] = accb + bb;
        }
        __syncthreads();
    }
}

// ---------------------------------------------------------------------------
// GEMM3: unchanged (small share of runtime).
// ---------------------------------------------------------------------------
__global__ __launch_bounds__(256) void gemm3_f32(
    const uint8_t* __restrict__ s,   // [M][250]
    const float* __restrict__ W3,    // [250][2]
    const float* __restrict__ b3,    // [2]
    float* __restrict__ cur3,        // [M][2]
    int M)
{
#pragma clang fp contract(off)
    __shared__ int wl[4][256];
    const int tid = threadIdx.x;
    const int wave = tid >> 6, lane = tid & 63;
    const long row = (long)blockIdx.x * 4 + wave;

    int base = 0;
    #pragma unroll
    for (int c = 0; c < 4; ++c) {
        const int k = c * 64 + lane;
        const bool sp = (k < HID) && s[row * HID + k];
        unsigned long long mask = __ballot(sp);
        if (sp) wl[wave][base + __popcll(mask & ((1ull << lane) - 1ull))] = k;
        base += __popcll(mask);      // wave-uniform
    }
    __syncthreads();

    if (lane < 2) {
        const int nact = base;
        float acc = 0.0f;
        for (int j = 0; j < nact; ++j)
            acc = acc + W3[wl[wave][j] * 2 + lane];
        cur3[row * 2 + lane] = acc + b3[lane];
    }
}

// ---------------------------------------------------------------------------
// Output scan: writes spikes (f32 0/1) and mem_rec (f32) into d_out.
// ---------------------------------------------------------------------------
__global__ __launch_bounds__(256) void scan3_f32(
    const float* __restrict__ cur3,  // [Tc][1024]
    float* __restrict__ state,       // [1024]
    float* __restrict__ out,         // spikes @0, mem @OUT_HALF
    int t0, int Tc)
{
#pragma clang fp contract(off)
    const int n = blockIdx.x * 256 + threadIdx.x;   // grid = 4*256 == 1024
    float m = state[n];
    for (int t = 0; t < Tc; ++t) {
        const float c = cur3[(long)t * 1024 + n];
        const float reset = (m > 1.0f) ? 1.0f : 0.0f;
        float tmp = 0.9f * m; tmp = tmp + c; m = tmp - reset;
        const long o = (long)(t0 + t) * 1024 + n;
        out[o] = (m > 1.0f) ? 1.0f : 0.0f;
        out[OUT_HALF + o] = m;
    }
    state[n] = m;
}

// ---------------------------------------------------------------------------
extern "C" void kernel_launch(void* const* d_in, const int* in_sizes, int n_in,
                              void* d_out, int out_size, void* d_ws, size_t ws_size,
                              hipStream_t stream) {
    const float* x  = (const float*)d_in[0];
    const float* W1 = (const float*)d_in[1];
    const float* b1 = (const float*)d_in[2];
    const float* W2 = (const float*)d_in[3];
    const float* b2 = (const float*)d_in[4];
    const float* W3 = (const float*)d_in[5];
    const float* b3 = (const float*)d_in[6];
    float* out = (float*)d_out;

    char* w = (char*)d_ws;
    size_t off = 0;
    auto alloc = [&](size_t bytes) -> void* {
        void* p = (void*)(w + off);
        off = (off + bytes + 255) & ~(size_t)255;
        return p;
    };

    float* m1 = (float*)alloc((size_t)N1 * 4);      // 512,000 B
    float* m2 = (float*)alloc((size_t)N1 * 4);      // 512,000 B
    float* m3 = (float*)alloc(1024 * 4);            // 4,096 B
    const size_t fixed = off;                        // states, zeroed each call

    // chunk size from workspace: per-step = cur3(4K) + sbuf(125K) + cur(500K)
    const size_t perT = 4096 + 128000 + 512000;
    long tc_budget = ((long)ws_size - (long)fixed - 4096) / (long)perT;
    int Tc = (int)(tc_budget < 1 ? 1 : (tc_budget > T_TOTAL ? T_TOTAL : tc_budget));

    float*   cur3 = (float*)alloc((size_t)Tc * 4096);
    uint8_t* sbuf = (uint8_t*)alloc((size_t)Tc * 128000);
    float*   cur  = (float*)alloc((size_t)Tc * 512000);

    hipMemsetAsync(d_ws, 0, fixed, stream);   // zero membrane states

    for (int t0 = 0; t0 < T_TOTAL; t0 += Tc) {
        const int tc = (T_TOTAL - t0 < Tc) ? (T_TOTAL - t0) : Tc;
        const int M = tc * BATCH;   // divisible by 512 -> by 64/16/4

        gemm1_v2<<<M / 64, 256, 0, stream>>>(x + (size_t)t0 * BATCH * NIN,
                                             W1, b1, cur, M);
        scan_f32<<<N1 / 256, 256, 0, stream>>>(cur, sbuf, m1, tc);
        gemm2_f32<<<M / 16, 256, 0, stream>>>(sbuf, W2, b2, cur, M);
        scan_f32<<<N1 / 256, 256, 0, stream>>>(cur, sbuf, m2, tc);
        gemm3_f32<<<M / 4, 256, 0, stream>>>(sbuf, W3, b3, cur3, M);
        scan3_f32<<<4, 256, 0, stream>>>(cur3, m3, out, t0, tc);
    }
}